// Round 10
// baseline (128.910 us; speedup 1.0000x reference)
//
#include <hip/hip_runtime.h>
#include <stdint.h>

// R10: revert R9's double-buffer (occupancy loss beat barrier savings) and
// replace k2's register staging with global_load_lds width=16 (direct
// global->LDS DMA, no VGPR round-trip). The XOR bank swizzle is folded into
// the *source* gather: staging lane L loads global chunk (L&7)^(L>>3), so the
// DMA's lane-contiguous LDS writes produce exactly the swizzled layout the
// fragment readers (aoff/boff) already expect.

typedef unsigned short u16;
typedef unsigned int u32;

#define B_    32
#define S_    64
#define H_    512
#define ATT_  128
#define NWIN  2016
#define NLEV  7
#define TLEV  6   // stored levels: 1..6

typedef __bf16 bf16x8 __attribute__((ext_vector_type(8)));
typedef float  f32x4  __attribute__((ext_vector_type(4)));

__device__ __forceinline__ float asf(u32 i) {
  union { u32 i; float f; } v; v.i = i; return v.f;
}
__device__ __forceinline__ u32 asu(float f) {
  union { float f; u32 i; } v; v.f = f; return v.i;
}
__device__ __forceinline__ float bf2f(u16 u) { return asf(((u32)u) << 16); }
__device__ __forceinline__ u16 f2bf(float f) {
  u32 i = asu(f);
  i += 0x7fffu + ((i >> 16) & 1u);   // round-to-nearest-even
  return (u16)(i >> 16);
}
// Exact bf16x2 max: halves viewed as f32 (low mantissa zero) -> v_max_f32
// exact; repack high halves. bf16 rounding is monotone, so the bf16 sparse
// table introduces no extra error vs rounding the pooled values.
__device__ __forceinline__ u32 bfmax2(u32 a, u32 b) {
  float a0 = asf(a << 16), a1 = asf(a & 0xffff0000u);
  float b0 = asf(b << 16), b1 = asf(b & 0xffff0000u);
  u32 m0 = asu(fmaxf(a0, b0)), m1 = asu(fmaxf(a1, b1));
  return (m1 & 0xffff0000u) | (m0 >> 16);
}
__device__ __forceinline__ uint4 bfmax8(uint4 a, uint4 b) {
  uint4 m;
  m.x = bfmax2(a.x, b.x); m.y = bfmax2(a.y, b.y);
  m.z = bfmax2(a.z, b.z); m.w = bfmax2(a.w, b.w);
  return m;
}
__device__ __forceinline__ bf16x8 as_bf16x8(uint4 v) {
  union { uint4 u; bf16x8 h; } c; c.u = v; return c.h;
}
// async global->LDS DMA, 16B per lane; LDS dst = base + lane*16 (HW rule)
__device__ __forceinline__ void gload_lds16(const u16* g, u16* l) {
  __builtin_amdgcn_global_load_lds(
      (const __attribute__((address_space(1))) u32*)g,
      (__attribute__((address_space(3))) u32*)l, 16, 0, 0);
}

// ============ k01: sparse table build + widx + W1^T (one launch) ============
// blocks [0,256): per-(hc,b) 64-column slab; level 0 stays in LDS only,
// levels 1..6 stream to global (level L at offset (L-1)*S*H).
// blocks [256,288): W1^T -> bf16 transpose; block 256 additionally emits widx.
__launch_bounds__(256)
__global__ void k01_init(const float* __restrict__ lstm, const float* __restrict__ W1,
                         u16* __restrict__ table, u16* __restrict__ w1t,
                         u16* __restrict__ widx) {
  int bid = blockIdx.x, tid = threadIdx.x;
  __shared__ u16 bufA[64 * 64], bufB[64 * 64];
  if (bid < 256) {
    int hc = bid & 7, b = bid >> 3;
    const float* src = lstm + (size_t)b * S_ * H_ + hc * 64;
    u16* tb = table + (size_t)b * TLEV * S_ * H_ + hc * 64;
    // level 0: fp32 -> bf16 into LDS only (never read from global)
    for (int t = tid; t < 64 * 16; t += 256) {
      int r = t >> 4, c4 = t & 15;
      float4 f = *reinterpret_cast<const float4*>(src + r * H_ + c4 * 4);
      ushort4 u;
      u.x = f2bf(f.x); u.y = f2bf(f.y); u.z = f2bf(f.z); u.w = f2bf(f.w);
      *reinterpret_cast<ushort4*>(&bufA[r * 64 + c4 * 4]) = u;
    }
    u16* pa = bufA; u16* pb = bufB;
    for (int k = 1; k < NLEV; ++k) {
      __syncthreads();
      int half = 1 << (k - 1);
      u16* dst_g = tb + (size_t)(k - 1) * S_ * H_;
      for (int t = tid; t < 64 * 16; t += 256) {
        int r = t >> 4, c4 = t & 15;
        int r2 = r + half; if (r2 > 63) r2 = 63;  // replicated tail, never read
        uint2 a  = *reinterpret_cast<const uint2*>(&pa[r  * 64 + c4 * 4]);
        uint2 bq = *reinterpret_cast<const uint2*>(&pa[r2 * 64 + c4 * 4]);
        uint2 m; m.x = bfmax2(a.x, bq.x); m.y = bfmax2(a.y, bq.y);
        *reinterpret_cast<uint2*>(&pb[r * 64 + c4 * 4]) = m;
        *reinterpret_cast<uint2*>(dst_g + r * H_ + c4 * 4) = m;
      }
      u16* tmp = pa; pa = pb; pb = tmp;
    }
  } else {
    int gb = bid - 256;   // 0..31
    if (gb == 0) {
      for (int n = tid; n < NWIN; n += 256) {
        int w = 2, rem = n;
        while (rem >= 65 - w) { rem -= 65 - w; ++w; }
        int s = rem;
        int k = 31 - __clz(w);
        int e2 = s + w - (1 << k);
        widx[n] = (u16)(s | (e2 << 6) | (k << 12));
      }
    }
    for (int q = tid; q < 2048; q += 256) {
      int idx = gb * 2048 + q;
      int n = idx >> 9, kq = idx & 511;
      w1t[idx] = f2bf(W1[kq * ATT_ + n]);
    }
  }
}

// ====== k2: pooled @ W1 (MFMA bf16) + bias + relu + @W2 -> scores ==========
// grid (21, 32), 256 thr. Tile: 96 windows x 128 att, K=512 in 8 chunks of 64.
// Single-buffered Ts/Bs (R8 structure; R9's dbuf cost occupancy), staged via
// global_load_lds: wave w, instr q covers rows w*32+q*8 .. +7; lane L loads
// global chunk (L&7)^(L>>3) of row +(L>>3), landing at LDS slot (L&7) — i.e.
// LDS slot c of row r holds global chunk c^(r&7), matching aoff/boff readers.
// A-fragments built in registers from the 2-level slab (a 96-window tile
// spans <=2 adjacent levels; per-lane addresses fixed across the K loop).
__launch_bounds__(256)
__attribute__((amdgpu_waves_per_eu(1, 4)))
__global__ void k2_scores(const u16* __restrict__ table, const u16* __restrict__ w1t,
                          const float* __restrict__ b1, const float* __restrict__ w2,
                          const u16* __restrict__ widx, float* __restrict__ scores) {
  const int b = blockIdx.y, mt = blockIdx.x;
  __shared__ u16 Ts[128 * 64];   // two level slabs, swizzled, 16 KB
  __shared__ u16 Bs[128 * 64];   // W1^T K-chunk, swizzled, 16 KB
  __shared__ u16 widx_l[96];
  __shared__ float b1s[128], w2s[128], sc[96];
  int tid = threadIdx.x;
  if (tid < 96) { widx_l[tid] = widx[mt * 96 + tid]; sc[tid] = 0.f; }
  if (tid < 128) { b1s[tid] = b1[tid]; w2s[tid] = w2[tid]; }
  __syncthreads();

  const int lv_lo = widx_l[0] >> 12;   // tile's lowest level (>=1); max lv_lo+1
  const u16* tb = table + (size_t)b * TLEV * S_ * H_ + (size_t)(lv_lo - 1) * S_ * H_;

  int wid = tid >> 6, lane = tid & 63;
  int wm = wid & 1, wn = wid >> 1;
  int lrow = lane & 15, quad = lane >> 4;

  // staging geometry: per-lane source offset inside an 8-row group
  int lr8 = lane >> 3, lc = lane & 7;
  size_t lane_goff = (size_t)lr8 * H_ + ((lc ^ lr8) * 8);
  const u16* tbase = tb  + (size_t)(wid * 32) * H_ + lane_goff;  // + q*8*H + kk
  const u16* bbase = w1t + (size_t)(wid * 32) * H_ + lane_goff;
  u16* ts_base = &Ts[(wid * 32) * 64];   // + q*8*64
  u16* bs_base = &Bs[(wid * 32) * 64];

  // A-fragment source addresses: 3 windows x {s,e2} x 2 ks-steps (constant)
  int aoff[3][2][2];
#pragma unroll
  for (int i = 0; i < 3; ++i) {
    int m = wm * 48 + i * 16 + lrow;
    int pk = widx_l[m];
    int s = pk & 63, e2 = (pk >> 6) & 63, lv = (pk >> 12) - lv_lo;  // 0 or 1
    int rs = lv * 64 + s, re = lv * 64 + e2;
#pragma unroll
    for (int k2i = 0; k2i < 2; ++k2i) {
      int c = quad + k2i * 4;
      aoff[i][k2i][0] = rs * 64 + ((c ^ (rs & 7)) * 8);
      aoff[i][k2i][1] = re * 64 + ((c ^ (re & 7)) * 8);
    }
  }
  // B-fragment addresses: 4 columns x 2 ks-steps (constant)
  int boff[4][2];
#pragma unroll
  for (int j = 0; j < 4; ++j) {
    int n = wn * 64 + j * 16 + lrow;
#pragma unroll
    for (int k2i = 0; k2i < 2; ++k2i) {
      int c = quad + k2i * 4;
      boff[j][k2i] = n * 64 + ((c ^ (n & 7)) * 8);
    }
  }

  f32x4 acc[3][4];
#pragma unroll
  for (int i = 0; i < 3; ++i)
#pragma unroll
    for (int j = 0; j < 4; ++j) acc[i][j] = (f32x4){0.f, 0.f, 0.f, 0.f};

  for (int kc = 0; kc < 8; ++kc) {
    int kk = kc * 64;
    __syncthreads();   // previous chunk's fragment reads complete
#pragma unroll
    for (int q = 0; q < 4; ++q) {
      gload_lds16(tbase + (size_t)q * 8 * H_ + kk, ts_base + q * 8 * 64);
      gload_lds16(bbase + (size_t)q * 8 * H_ + kk, bs_base + q * 8 * 64);
    }
    __syncthreads();   // vmcnt(0) drain: DMA data visible in LDS
#pragma unroll
    for (int k2i = 0; k2i < 2; ++k2i) {
      bf16x8 af[3], bfr[4];
#pragma unroll
      for (int i = 0; i < 3; ++i) {
        uint4 va = *reinterpret_cast<const uint4*>(&Ts[aoff[i][k2i][0]]);
        uint4 vb = *reinterpret_cast<const uint4*>(&Ts[aoff[i][k2i][1]]);
        af[i] = as_bf16x8(bfmax8(va, vb));
      }
#pragma unroll
      for (int j = 0; j < 4; ++j)
        bfr[j] = *reinterpret_cast<const bf16x8*>(&Bs[boff[j][k2i]]);
#pragma unroll
      for (int i = 0; i < 3; ++i)
#pragma unroll
        for (int j = 0; j < 4; ++j)
          acc[i][j] = __builtin_amdgcn_mfma_f32_16x16x32_bf16(af[i], bfr[j], acc[i][j], 0, 0, 0);
    }
  }

  // epilogue: score[m] = sum_n relu(hid+b1)*w2 (b2 dropped: softmax-invariant)
#pragma unroll
  for (int i = 0; i < 3; ++i) {
#pragma unroll
    for (int r = 0; r < 4; ++r) {
      float p = 0.f;
#pragma unroll
      for (int j = 0; j < 4; ++j) {
        int n = wn * 64 + j * 16 + lrow;
        float v = acc[i][j][r] + b1s[n];
        p += (v > 0.f ? v : 0.f) * w2s[n];
      }
      p += __shfl_xor(p, 1, 16);
      p += __shfl_xor(p, 2, 16);
      p += __shfl_xor(p, 4, 16);
      p += __shfl_xor(p, 8, 16);
      if (lrow == 0) atomicAdd(&sc[wm * 48 + i * 16 + quad * 4 + r], p);
    }
  }
  __syncthreads();
  if (tid < 96) scores[b * NWIN + mt * 96 + tid] = sc[tid];
}

// ========= k34: per-block softmax (redundant) + attn-weighted sum ==========
// grid (16, 32), 256 thr; 32-wide h slice per block. Softmax recomputed
// per block from scores (8 exp/thread + two wave reductions); 1/sum folded
// into the final store. Table holds levels 1..6.
__launch_bounds__(256)
__global__ void k34_out(const u16* __restrict__ table, const float* __restrict__ scores,
                        const u16* __restrict__ widx, float* __restrict__ out) {
  int hc = blockIdx.x, b = blockIdx.y, tid = threadIdx.x;
  __shared__ u16 Tl[6 * 64 * 32];       // 24 KB: levels 1..6, 32-col slice
  __shared__ float attn_l[NWIN];        // 8 KB, unnormalized exp
  __shared__ u16 widx_l[NWIN];          // 4 KB
  __shared__ float red[8][32];
  __shared__ float wredM[4], wredS[4];
  const u16* tb = table + (size_t)b * TLEV * S_ * H_;   // levels 1..6
  int h0 = hc * 32;
  int lane = tid & 63, wid = tid >> 6;

  for (int t = tid; t < 6 * 64 * 4; t += 256) {
    int row = t >> 2, c = t & 3;
    uint4 v = *reinterpret_cast<const uint4*>(tb + row * H_ + h0 + c * 8);
    *reinterpret_cast<uint4*>(&Tl[row * 32 + c * 8]) = v;
  }
  for (int n = tid; n < NWIN; n += 256) widx_l[n] = widx[n];

  float mx = -1e30f;
  for (int n = tid; n < NWIN; n += 256) {
    float v = scores[b * NWIN + n];
    attn_l[n] = v;
    mx = fmaxf(mx, v);
  }
#pragma unroll
  for (int off = 32; off > 0; off >>= 1) mx = fmaxf(mx, __shfl_xor(mx, off, 64));
  if (lane == 0) wredM[wid] = mx;
  __syncthreads();   // also covers the Tl / widx_l / attn_l staging above
  mx = fmaxf(fmaxf(wredM[0], wredM[1]), fmaxf(wredM[2], wredM[3]));
  float sum = 0.f;
  for (int n = tid; n < NWIN; n += 256) {
    float e = __expf(attn_l[n] - mx);
    attn_l[n] = e;
    sum += e;
  }
#pragma unroll
  for (int off = 32; off > 0; off >>= 1) sum += __shfl_xor(sum, off, 64);
  if (lane == 0) wredS[wid] = sum;
  __syncthreads();
  float inv = 1.f / (wredS[0] + wredS[1] + wredS[2] + wredS[3]);

  int h = tid & 31, g = tid >> 5;   // 8 groups x 252 windows each
  float acc = 0.f;
  for (int n = g * 252; n < g * 252 + 252; ++n) {
    int pk = widx_l[n];
    int s = pk & 63, e2 = (pk >> 6) & 63, lv = pk >> 12;
    float va = bf2f(Tl[((lv - 1) * 64 + s) * 32 + h]);
    float vb = bf2f(Tl[((lv - 1) * 64 + e2) * 32 + h]);
    acc += attn_l[n] * fmaxf(va, vb);
  }
  red[g][h] = acc;
  __syncthreads();
  if (tid < 32) {
    float s2 = 0.f;
#pragma unroll
    for (int g2 = 0; g2 < 8; ++g2) s2 += red[g2][tid];
    out[b * H_ + h0 + tid] = s2 * inv;
  }
}

// ================================ launch ===================================
extern "C" void kernel_launch(void* const* d_in, const int* in_sizes, int n_in,
                              void* d_out, int out_size, void* d_ws, size_t ws_size,
                              hipStream_t stream) {
  const float* lstm = (const float*)d_in[0];
  const float* W1   = (const float*)d_in[1];
  const float* b1   = (const float*)d_in[2];
  const float* W2   = (const float*)d_in[3];
  // d_in[4] = b2: uniform shift ahead of softmax -> no output effect, unused.
  float* out = (float*)d_out;

  char* ws = (char*)d_ws;
  // ws layout: widx u16 [0,4096) | w1t bf16 [4096,135168)
  //            | table bf16 levels 1..6 (12.58 MB) | scores f32 (258048 B)
  u16*   widx   = (u16*)(ws + 0);
  u16*   w1t    = (u16*)(ws + 4096);
  u16*   table  = (u16*)(ws + 135168);
  float* scores = (float*)(ws + 12718080);

  k01_init <<<288, 256, 0, stream>>>(lstm, W1, table, w1t, widx);
  k2_scores<<<dim3(21, B_), 256, 0, stream>>>(table, w1t, b1, W2, widx, scores);
  k34_out  <<<dim3(16, B_), 256, 0, stream>>>(table, scores, widx, out);
}

// Round 11
// 116.632 us; speedup vs baseline: 1.1053x; 1.1053x over previous
//
#include <hip/hip_runtime.h>
#include <stdint.h>

// R11: k2 re-tiled 96x128 -> 64x128 (grid 672 -> 1024 = exactly 4 blocks/CU,
// full co-residency in one dispatch round) with 4x1 wave grid in M: no
// A-fragment redundancy (2 bfmax8/lane/chunk vs 6), acc 48->32 VGPRs, and a
// direct per-wave global score store (no LDS sc / atomicAdd). Staging reverts
// to R8's register prefetch-distance-1 (best measured; R10's DMA lost the
// overlap and exposed full load latency at the vmcnt(0) barrier drain).

typedef unsigned short u16;
typedef unsigned int u32;

#define B_    32
#define S_    64
#define H_    512
#define ATT_  128
#define NWIN  2016
#define NLEV  7
#define TLEV  6   // stored levels: 1..6

typedef __bf16 bf16x8 __attribute__((ext_vector_type(8)));
typedef float  f32x4  __attribute__((ext_vector_type(4)));

__device__ __forceinline__ float asf(u32 i) {
  union { u32 i; float f; } v; v.i = i; return v.f;
}
__device__ __forceinline__ u32 asu(float f) {
  union { float f; u32 i; } v; v.f = f; return v.i;
}
__device__ __forceinline__ float bf2f(u16 u) { return asf(((u32)u) << 16); }
__device__ __forceinline__ u16 f2bf(float f) {
  u32 i = asu(f);
  i += 0x7fffu + ((i >> 16) & 1u);   // round-to-nearest-even
  return (u16)(i >> 16);
}
// Exact bf16x2 max: halves viewed as f32 (low mantissa zero) -> v_max_f32
// exact; repack high halves. bf16 rounding is monotone, so the bf16 sparse
// table introduces no extra error vs rounding the pooled values.
__device__ __forceinline__ u32 bfmax2(u32 a, u32 b) {
  float a0 = asf(a << 16), a1 = asf(a & 0xffff0000u);
  float b0 = asf(b << 16), b1 = asf(b & 0xffff0000u);
  u32 m0 = asu(fmaxf(a0, b0)), m1 = asu(fmaxf(a1, b1));
  return (m1 & 0xffff0000u) | (m0 >> 16);
}
__device__ __forceinline__ uint4 bfmax8(uint4 a, uint4 b) {
  uint4 m;
  m.x = bfmax2(a.x, b.x); m.y = bfmax2(a.y, b.y);
  m.z = bfmax2(a.z, b.z); m.w = bfmax2(a.w, b.w);
  return m;
}
__device__ __forceinline__ bf16x8 as_bf16x8(uint4 v) {
  union { uint4 u; bf16x8 h; } c; c.u = v; return c.h;
}

// ============ k01: sparse table build + widx + W1^T (one launch) ============
// blocks [0,256): per-(hc,b) 64-column slab; level 0 stays in LDS only,
// levels 1..6 stream to global (level L at offset (L-1)*S*H).
// blocks [256,288): W1^T -> bf16 transpose; block 256 additionally emits widx.
__launch_bounds__(256)
__global__ void k01_init(const float* __restrict__ lstm, const float* __restrict__ W1,
                         u16* __restrict__ table, u16* __restrict__ w1t,
                         u16* __restrict__ widx) {
  int bid = blockIdx.x, tid = threadIdx.x;
  __shared__ u16 bufA[64 * 64], bufB[64 * 64];
  if (bid < 256) {
    int hc = bid & 7, b = bid >> 3;
    const float* src = lstm + (size_t)b * S_ * H_ + hc * 64;
    u16* tb = table + (size_t)b * TLEV * S_ * H_ + hc * 64;
    // level 0: fp32 -> bf16 into LDS only (never read from global)
    for (int t = tid; t < 64 * 16; t += 256) {
      int r = t >> 4, c4 = t & 15;
      float4 f = *reinterpret_cast<const float4*>(src + r * H_ + c4 * 4);
      ushort4 u;
      u.x = f2bf(f.x); u.y = f2bf(f.y); u.z = f2bf(f.z); u.w = f2bf(f.w);
      *reinterpret_cast<ushort4*>(&bufA[r * 64 + c4 * 4]) = u;
    }
    u16* pa = bufA; u16* pb = bufB;
    for (int k = 1; k < NLEV; ++k) {
      __syncthreads();
      int half = 1 << (k - 1);
      u16* dst_g = tb + (size_t)(k - 1) * S_ * H_;
      for (int t = tid; t < 64 * 16; t += 256) {
        int r = t >> 4, c4 = t & 15;
        int r2 = r + half; if (r2 > 63) r2 = 63;  // replicated tail, never read
        uint2 a  = *reinterpret_cast<const uint2*>(&pa[r  * 64 + c4 * 4]);
        uint2 bq = *reinterpret_cast<const uint2*>(&pa[r2 * 64 + c4 * 4]);
        uint2 m; m.x = bfmax2(a.x, bq.x); m.y = bfmax2(a.y, bq.y);
        *reinterpret_cast<uint2*>(&pb[r * 64 + c4 * 4]) = m;
        *reinterpret_cast<uint2*>(dst_g + r * H_ + c4 * 4) = m;
      }
      u16* tmp = pa; pa = pb; pb = tmp;
    }
  } else {
    int gb = bid - 256;   // 0..31
    if (gb == 0) {
      for (int n = tid; n < NWIN; n += 256) {
        int w = 2, rem = n;
        while (rem >= 65 - w) { rem -= 65 - w; ++w; }
        int s = rem;
        int k = 31 - __clz(w);
        int e2 = s + w - (1 << k);
        widx[n] = (u16)(s | (e2 << 6) | (k << 12));
      }
    }
    for (int q = tid; q < 2048; q += 256) {
      int idx = gb * 2048 + q;
      int n = idx >> 9, kq = idx & 511;
      w1t[idx] = f2bf(W1[kq * ATT_ + n]);
    }
  }
}

// ====== k2: pooled @ W1 (MFMA bf16) + bias + relu + @W2 -> scores ==========
// grid (32, 32), 256 thr. Tile: 64 windows x 128 att, K=512 in 8 chunks of 64.
// Wave grid 4x1 in M: wave w owns windows [16w,16w+16) x all 128 att.
// Single-buffered XOR-swizzled Ts/Bs, register staging with prefetch-1.
// A 64-window tile spans <=2 adjacent sparse-table levels (level run lengths
// 125/238/428/664/560/1; tile [1984,2048) spans 5->6 only). Windows padded
// to 2048 via clamped widx; stores masked at n >= 2016.
__launch_bounds__(256)
__attribute__((amdgpu_waves_per_eu(1, 4)))
__global__ void k2_scores(const u16* __restrict__ table, const u16* __restrict__ w1t,
                          const float* __restrict__ b1, const float* __restrict__ w2,
                          const u16* __restrict__ widx, float* __restrict__ scores) {
  const int b = blockIdx.y, mt = blockIdx.x;
  __shared__ u16 Ts[128 * 64];   // two level slabs, swizzled, 16 KB
  __shared__ u16 Bs[128 * 64];   // W1^T K-chunk, swizzled, 16 KB
  __shared__ u16 widx_l[64];
  __shared__ float b1s[128], w2s[128];
  int tid = threadIdx.x;
  if (tid < 64) {
    int n = mt * 64 + tid; if (n > NWIN - 1) n = NWIN - 1;  // pad-clamp
    widx_l[tid] = widx[n];
  }
  if (tid < 128) { b1s[tid] = b1[tid]; w2s[tid] = w2[tid]; }
  __syncthreads();

  const int lv_lo = widx_l[0] >> 12;   // tile's lowest level (>=1); max lv_lo+1
  const u16* tb = table + (size_t)b * TLEV * S_ * H_ + (size_t)(lv_lo - 1) * S_ * H_;

  // staging slots, scalarized (R8 pattern): slot i covers t = tid + i*256,
  // row = t>>3 in 0..127, c = t&7; swizzled LDS dst = row*64 + ((c^(row&7))*8)
  int t0 = tid, t1 = tid + 256, t2 = tid + 512, t3 = tid + 768;
  int r0 = t0 >> 3, r1 = t1 >> 3, r2 = t2 >> 3, r3 = t3 >> 3;
  int c0 = t0 & 7,  c1 = t1 & 7,  c2 = t2 & 7,  c3 = t3 & 7;
  const u16* ts0 = tb + r0 * H_ + c0 * 8;
  const u16* ts1 = tb + r1 * H_ + c1 * 8;
  const u16* ts2 = tb + r2 * H_ + c2 * 8;
  const u16* ts3 = tb + r3 * H_ + c3 * 8;
  const u16* bs0 = w1t + r0 * H_ + c0 * 8;
  const u16* bs1 = w1t + r1 * H_ + c1 * 8;
  const u16* bs2 = w1t + r2 * H_ + c2 * 8;
  const u16* bs3 = w1t + r3 * H_ + c3 * 8;
  int sd0 = r0 * 64 + ((c0 ^ (r0 & 7)) * 8);
  int sd1 = r1 * 64 + ((c1 ^ (r1 & 7)) * 8);
  int sd2 = r2 * 64 + ((c2 ^ (r2 & 7)) * 8);
  int sd3 = r3 * 64 + ((c3 ^ (r3 & 7)) * 8);

  int wid = tid >> 6, lane = tid & 63;
  int lrow = lane & 15, quad = lane >> 4;

  // A-fragment addresses: this wave's window m = wid*16 + lrow; {s,e2} x k2i
  int aoff[2][2];
  {
    int pk = widx_l[wid * 16 + lrow];
    int s = pk & 63, e2 = (pk >> 6) & 63, lv = (pk >> 12) - lv_lo;  // 0 or 1
    int rs = lv * 64 + s, re = lv * 64 + e2;
#pragma unroll
    for (int k2i = 0; k2i < 2; ++k2i) {
      int c = quad + k2i * 4;
      aoff[k2i][0] = rs * 64 + ((c ^ (rs & 7)) * 8);
      aoff[k2i][1] = re * 64 + ((c ^ (re & 7)) * 8);
    }
  }
  // B-fragment addresses: 8 columns x 2 ks-steps (constant)
  int boff[8][2];
#pragma unroll
  for (int j = 0; j < 8; ++j) {
    int n = j * 16 + lrow;
#pragma unroll
    for (int k2i = 0; k2i < 2; ++k2i) {
      int c = quad + k2i * 4;
      boff[j][k2i] = n * 64 + ((c ^ (n & 7)) * 8);
    }
  }

  uint4 rT0, rT1, rT2, rT3, rB0, rB1, rB2, rB3;

#define ISSUE(KK) do { \
  rT0 = *reinterpret_cast<const uint4*>(ts0 + (KK)); \
  rT1 = *reinterpret_cast<const uint4*>(ts1 + (KK)); \
  rT2 = *reinterpret_cast<const uint4*>(ts2 + (KK)); \
  rT3 = *reinterpret_cast<const uint4*>(ts3 + (KK)); \
  rB0 = *reinterpret_cast<const uint4*>(bs0 + (KK)); \
  rB1 = *reinterpret_cast<const uint4*>(bs1 + (KK)); \
  rB2 = *reinterpret_cast<const uint4*>(bs2 + (KK)); \
  rB3 = *reinterpret_cast<const uint4*>(bs3 + (KK)); \
} while (0)

#define STAGE() do { \
  *reinterpret_cast<uint4*>(&Ts[sd0]) = rT0; \
  *reinterpret_cast<uint4*>(&Ts[sd1]) = rT1; \
  *reinterpret_cast<uint4*>(&Ts[sd2]) = rT2; \
  *reinterpret_cast<uint4*>(&Ts[sd3]) = rT3; \
  *reinterpret_cast<uint4*>(&Bs[sd0]) = rB0; \
  *reinterpret_cast<uint4*>(&Bs[sd1]) = rB1; \
  *reinterpret_cast<uint4*>(&Bs[sd2]) = rB2; \
  *reinterpret_cast<uint4*>(&Bs[sd3]) = rB3; \
} while (0)

  ISSUE(0);

  f32x4 acc[8];
#pragma unroll
  for (int j = 0; j < 8; ++j) acc[j] = (f32x4){0.f, 0.f, 0.f, 0.f};

  for (int kc = 0; kc < 7; ++kc) {
    __syncthreads();   // previous chunk's fragment reads complete
    STAGE();
    __syncthreads();
    ISSUE((kc + 1) * 64);   // hides under the MFMA chunk below
#pragma unroll
    for (int k2i = 0; k2i < 2; ++k2i) {
      uint4 va = *reinterpret_cast<const uint4*>(&Ts[aoff[k2i][0]]);
      uint4 vb = *reinterpret_cast<const uint4*>(&Ts[aoff[k2i][1]]);
      bf16x8 af = as_bf16x8(bfmax8(va, vb));
#pragma unroll
      for (int j = 0; j < 8; ++j) {
        bf16x8 bfr = *reinterpret_cast<const bf16x8*>(&Bs[boff[j][k2i]]);
        acc[j] = __builtin_amdgcn_mfma_f32_16x16x32_bf16(af, bfr, acc[j], 0, 0, 0);
      }
    }
  }
  __syncthreads();
  STAGE();
  __syncthreads();
#pragma unroll
  for (int k2i = 0; k2i < 2; ++k2i) {
    uint4 va = *reinterpret_cast<const uint4*>(&Ts[aoff[k2i][0]]);
    uint4 vb = *reinterpret_cast<const uint4*>(&Ts[aoff[k2i][1]]);
    bf16x8 af = as_bf16x8(bfmax8(va, vb));
#pragma unroll
    for (int j = 0; j < 8; ++j) {
      bf16x8 bfr = *reinterpret_cast<const bf16x8*>(&Bs[boff[j][k2i]]);
      acc[j] = __builtin_amdgcn_mfma_f32_16x16x32_bf16(af, bfr, acc[j], 0, 0, 0);
    }
  }

#undef ISSUE
#undef STAGE

  // epilogue: score[m] = sum_n relu(hid+b1)*w2 (b2 dropped: softmax-invariant)
  // C layout: row = quad*4 + r, col = lrow. Reduce over 128 cols = 8 j-frags
  // in-register + 16-lane shfl; lane lrow==0 stores row quad*4+r directly.
#pragma unroll
  for (int r = 0; r < 4; ++r) {
    float p = 0.f;
#pragma unroll
    for (int j = 0; j < 8; ++j) {
      int n = j * 16 + lrow;
      float v = acc[j][r] + b1s[n];
      p += (v > 0.f ? v : 0.f) * w2s[n];
    }
    p += __shfl_xor(p, 1, 16);
    p += __shfl_xor(p, 2, 16);
    p += __shfl_xor(p, 4, 16);
    p += __shfl_xor(p, 8, 16);
    if (lrow == 0) {
      int nw = mt * 64 + wid * 16 + quad * 4 + r;
      if (nw < NWIN) scores[b * NWIN + nw] = p;
    }
  }
}

// ========= k34: per-block softmax (redundant) + attn-weighted sum ==========
// grid (16, 32), 256 thr; 32-wide h slice per block. Softmax recomputed
// per block from scores (8 exp/thread + two wave reductions); 1/sum folded
// into the final store. Table holds levels 1..6.
__launch_bounds__(256)
__global__ void k34_out(const u16* __restrict__ table, const float* __restrict__ scores,
                        const u16* __restrict__ widx, float* __restrict__ out) {
  int hc = blockIdx.x, b = blockIdx.y, tid = threadIdx.x;
  __shared__ u16 Tl[6 * 64 * 32];       // 24 KB: levels 1..6, 32-col slice
  __shared__ float attn_l[NWIN];        // 8 KB, unnormalized exp
  __shared__ u16 widx_l[NWIN];          // 4 KB
  __shared__ float red[8][32];
  __shared__ float wredM[4], wredS[4];
  const u16* tb = table + (size_t)b * TLEV * S_ * H_;   // levels 1..6
  int h0 = hc * 32;
  int lane = tid & 63, wid = tid >> 6;

  for (int t = tid; t < 6 * 64 * 4; t += 256) {
    int row = t >> 2, c = t & 3;
    uint4 v = *reinterpret_cast<const uint4*>(tb + row * H_ + h0 + c * 8);
    *reinterpret_cast<uint4*>(&Tl[row * 32 + c * 8]) = v;
  }
  for (int n = tid; n < NWIN; n += 256) widx_l[n] = widx[n];

  float mx = -1e30f;
  for (int n = tid; n < NWIN; n += 256) {
    float v = scores[b * NWIN + n];
    attn_l[n] = v;
    mx = fmaxf(mx, v);
  }
#pragma unroll
  for (int off = 32; off > 0; off >>= 1) mx = fmaxf(mx, __shfl_xor(mx, off, 64));
  if (lane == 0) wredM[wid] = mx;
  __syncthreads();   // also covers the Tl / widx_l / attn_l staging above
  mx = fmaxf(fmaxf(wredM[0], wredM[1]), fmaxf(wredM[2], wredM[3]));
  float sum = 0.f;
  for (int n = tid; n < NWIN; n += 256) {
    float e = __expf(attn_l[n] - mx);
    attn_l[n] = e;
    sum += e;
  }
#pragma unroll
  for (int off = 32; off > 0; off >>= 1) sum += __shfl_xor(sum, off, 64);
  if (lane == 0) wredS[wid] = sum;
  __syncthreads();
  float inv = 1.f / (wredS[0] + wredS[1] + wredS[2] + wredS[3]);

  int h = tid & 31, g = tid >> 5;   // 8 groups x 252 windows each
  float acc = 0.f;
  for (int n = g * 252; n < g * 252 + 252; ++n) {
    int pk = widx_l[n];
    int s = pk & 63, e2 = (pk >> 6) & 63, lv = pk >> 12;
    float va = bf2f(Tl[((lv - 1) * 64 + s) * 32 + h]);
    float vb = bf2f(Tl[((lv - 1) * 64 + e2) * 32 + h]);
    acc += attn_l[n] * fmaxf(va, vb);
  }
  red[g][h] = acc;
  __syncthreads();
  if (tid < 32) {
    float s2 = 0.f;
#pragma unroll
    for (int g2 = 0; g2 < 8; ++g2) s2 += red[g2][tid];
    out[b * H_ + h0 + tid] = s2 * inv;
  }
}

// ================================ launch ===================================
extern "C" void kernel_launch(void* const* d_in, const int* in_sizes, int n_in,
                              void* d_out, int out_size, void* d_ws, size_t ws_size,
                              hipStream_t stream) {
  const float* lstm = (const float*)d_in[0];
  const float* W1   = (const float*)d_in[1];
  const float* b1   = (const float*)d_in[2];
  const float* W2   = (const float*)d_in[3];
  // d_in[4] = b2: uniform shift ahead of softmax -> no output effect, unused.
  float* out = (float*)d_out;

  char* ws = (char*)d_ws;
  // ws layout: widx u16 [0,4096) | w1t bf16 [4096,135168)
  //            | table bf16 levels 1..6 (12.58 MB) | scores f32 (258048 B)
  u16*   widx   = (u16*)(ws + 0);
  u16*   w1t    = (u16*)(ws + 4096);
  u16*   table  = (u16*)(ws + 135168);
  float* scores = (float*)(ws + 12718080);

  k01_init <<<288, 256, 0, stream>>>(lstm, W1, table, w1t, widx);
  k2_scores<<<dim3(32, B_), 256, 0, stream>>>(table, w1t, b1, W2, widx, scores);
  k34_out  <<<dim3(16, B_), 256, 0, stream>>>(table, scores, widx, out);
}